// Round 15
// baseline (180.839 us; speedup 1.0000x reference)
//
#include <hip/hip_runtime.h>
#include <math.h>

#define DIMD 768
#define DSTATE 64
#define DINNER 1536
#define DTRANK 48
#define BATCH 2
#define SEQL 1024
#define NTOK (BATCH*SEQL)
#define XDBL_P 192              // padded x_dbl row stride (176 -> 192)
#define EPSV 1e-5f

typedef __attribute__((ext_vector_type(8))) short bf16x8;
typedef __attribute__((ext_vector_type(4))) short s16x4;
typedef __attribute__((ext_vector_type(4))) float f32x4;

__device__ inline short f2bf(float f) {             // RTNE f32 -> bf16
  unsigned u = __float_as_uint(f);
  u = u + 0x7FFFu + ((u >> 16) & 1u);
  return (short)(u >> 16);
}
__device__ inline float bf2f(short s) {
  return __uint_as_float(((unsigned)(unsigned short)s) << 16);
}

// ---------------- prep: LayerNorm->bf16 (blocks 0..511) + vectorized weight cvt ----------------
#define NW_IN  (3072*768)
#define NW_OUT (768*1536)
#define NW_XP  (192*1536)
#define LN_BLOCKS (NTOK/4)
#define CVT_BLOCKS ((NW_IN+NW_OUT+NW_XP)/4/256)
__global__ __launch_bounds__(256) void prep_kernel(const float* __restrict__ x,
                                                   const float* __restrict__ gamma,
                                                   const float* __restrict__ beta,
                                                   short* __restrict__ xnq,
                                                   const float* __restrict__ Win,
                                                   const float* __restrict__ Wout,
                                                   const float* __restrict__ Wx,
                                                   short* __restrict__ qin,
                                                   short* __restrict__ qout,
                                                   short* __restrict__ qx) {
  if (blockIdx.x < LN_BLOCKS) {
    int wave = threadIdx.x >> 6;
    int lane = threadIdx.x & 63;
    int row = blockIdx.x * 4 + wave;
    const float* xr = x + (size_t)row * DIMD;
    float v[12];
    float s = 0.f, ss = 0.f;
#pragma unroll
    for (int i = 0; i < 12; ++i) {
      v[i] = xr[lane + i*64];
      s += v[i];
      ss += v[i]*v[i];
    }
#pragma unroll
    for (int m = 1; m < 64; m <<= 1) {
      s  += __shfl_xor(s, m);
      ss += __shfl_xor(ss, m);
    }
    float mu   = s * (1.f/DIMD);
    float var  = ss * (1.f/DIMD) - mu*mu;
    float rstd = rsqrtf(var + EPSV);
    short* o = xnq + (size_t)row * DIMD;
#pragma unroll
    for (int i = 0; i < 12; ++i) {
      int j = lane + i*64;
      o[j] = f2bf((v[i] - mu) * rstd * gamma[j] + beta[j]);
    }
    return;
  }
  int e = ((blockIdx.x - LN_BLOCKS) * 256 + threadIdx.x) * 4;   // 4 elems/thread
  const float* src;
  short* dst;
  if (e < NW_IN) { src = Win + e; dst = qin + e; }
  else if ((e -= NW_IN) < NW_OUT) { src = Wout + e; dst = qout + e; }
  else if ((e -= NW_OUT) < NW_XP) {
    int r = e / 1536;
    dst = qx + e;
    if (r >= 176) { *(s16x4*)dst = (s16x4){0,0,0,0}; return; }
    src = Wx + e;
  } else return;
  float4 v = *(const float4*)src;
  *(s16x4*)dst = (s16x4){f2bf(v.x), f2bf(v.y), f2bf(v.z), f2bf(v.w)};
}

// ---------------- bf16 MFMA NT GEMM, optional split-K, optional bf16 C ----------------
template<int BN, bool BF16OUT>
__global__ __launch_bounds__(256) void gemm_mfma(const short* __restrict__ A,
                                                 const short* __restrict__ B,
                                                 float* __restrict__ C, int ldc,
                                                 int Kfull, int Kchunk, size_t partStride) {
  constexpr int BM = 128, BK = 64;
  constexpr int WN = (BN == 128) ? 2 : 1;
  constexpr int WM = 4 / WN;
  constexpr int MFR = BM / (WM * 16);
  constexpr int NFR = BN / (WN * 16);
  constexpr int BSW = (BN * BK * 2) / 4096;
  __shared__ short As[BM * BK];
  __shared__ short Bs[BN * BK];
  const int tid  = threadIdx.x;
  const int wave = tid >> 6, lane = tid & 63;
  const int m0 = blockIdx.y * BM;
  const int n0 = blockIdx.x * BN;
  const int wm = wave / WN, wn = wave % WN;
  const int kBeg = blockIdx.z * Kchunk;
  const int kEnd = kBeg + Kchunk;
  C += (size_t)blockIdx.z * partStride;

  const short* aSrc = A + (size_t)(m0 + (tid >> 3)) * Kfull + (tid & 7) * 8;
  const short* bSrc = B + (size_t)(n0 + (tid >> 3)) * Kfull + (tid & 7) * 8;

  f32x4 acc[MFR][NFR];
#pragma unroll
  for (int i = 0; i < MFR; ++i)
#pragma unroll
    for (int j = 0; j < NFR; ++j)
      acc[i][j] = (f32x4){0.f, 0.f, 0.f, 0.f};

  for (int k0 = kBeg; k0 < kEnd; k0 += BK) {
#pragma unroll
    for (int s = 0; s < 4; ++s)
      __builtin_amdgcn_global_load_lds(
        (const __attribute__((address_space(1))) void*)(aSrc + (size_t)s*32*Kfull + k0),
        (__attribute__((address_space(3))) void*)((char*)As + s*4096 + wave*1024),
        16, 0, 0);
#pragma unroll
    for (int s = 0; s < BSW; ++s)
      __builtin_amdgcn_global_load_lds(
        (const __attribute__((address_space(1))) void*)(bSrc + (size_t)s*32*Kfull + k0),
        (__attribute__((address_space(3))) void*)((char*)Bs + s*4096 + wave*1024),
        16, 0, 0);
    __syncthreads();

#pragma unroll
    for (int kk = 0; kk < 2; ++kk) {
      bf16x8 af[MFR], bfr[NFR];
#pragma unroll
      for (int i = 0; i < MFR; ++i) {
        int r = wm * (BM / WM) + i * 16 + (lane & 15);
        af[i] = *(const bf16x8*)&As[r * BK + kk * 32 + (lane >> 4) * 8];
      }
#pragma unroll
      for (int j = 0; j < NFR; ++j) {
        int r = wn * (BN / WN) + j * 16 + (lane & 15);
        bfr[j] = *(const bf16x8*)&Bs[r * BK + kk * 32 + (lane >> 4) * 8];
      }
#pragma unroll
      for (int i = 0; i < MFR; ++i)
#pragma unroll
        for (int j = 0; j < NFR; ++j)
          acc[i][j] = __builtin_amdgcn_mfma_f32_16x16x32_bf16(af[i], bfr[j], acc[i][j], 0, 0, 0);
    }
    __syncthreads();
  }

  const int cn = lane & 15, cr4 = (lane >> 4) * 4;
#pragma unroll
  for (int i = 0; i < MFR; ++i)
#pragma unroll
    for (int j = 0; j < NFR; ++j)
#pragma unroll
      for (int r = 0; r < 4; ++r) {
        int m = m0 + wm * (BM / WM) + i * 16 + cr4 + r;
        int n = n0 + wn * (BN / WN) + j * 16 + cn;
        if constexpr (BF16OUT)
          ((short*)C)[(size_t)m * ldc + n] = f2bf(acc[i][j][r]);
        else
          C[(size_t)m * ldc + n] = acc[i][j][r];
      }
}

// ---------------- split-K partial reduce: out = p0+p1+p2+p3 (fixed order) ----------------
__global__ __launch_bounds__(256) void reduce4_kernel(const float* __restrict__ p,
                                                      float* __restrict__ outb) {
  const int n4 = NTOK * XDBL_P / 4;
  int i = blockIdx.x * 256 + threadIdx.x;
  if (i >= n4) return;
  const float4* p4 = (const float4*)p;
  float4 a = p4[i];
  float4 b = p4[i + n4];
  float4 c = p4[i + 2*n4];
  float4 d = p4[i + 3*n4];
  float4 r;
  r.x = ((a.x + b.x) + c.x) + d.x;
  r.y = ((a.y + b.y) + c.y) + d.y;
  r.z = ((a.z + b.z) + c.z) + d.z;
  r.w = ((a.w + b.w) + c.w) + d.w;
  ((float4*)outb)[i] = r;
}

// ---------------- fp32 NT GEMM. ACT: 0 none, 2 = bias[m]+softplus (row bias) ----------------
template<int ACT>
__global__ __launch_bounds__(256) void gemm_nt(const float* __restrict__ A, int lda,
                                               const float* __restrict__ W, int ldw,
                                               const float* __restrict__ bias,
                                               float* __restrict__ C, int ldc,
                                               int M, int N, int K) {
  __shared__ float Asl[16][68];
  __shared__ float Wsl[16][68];
  int tid = threadIdx.x;
  int m0 = blockIdx.y * 64;
  int n0 = blockIdx.x * 64;
  int lrow = tid >> 2;
  int lq   = tid & 3;
  int tx = tid & 15;
  int ty = tid >> 4;
  float acc[4][4] = {{0.f}};

  for (int k0 = 0; k0 < K; k0 += 16) {
    float4 av = make_float4(0.f,0.f,0.f,0.f);
    int ar = m0 + lrow;
    if (ar < M) av = *(const float4*)(A + (size_t)ar*lda + k0 + lq*4);
    float4 wv = make_float4(0.f,0.f,0.f,0.f);
    int wr = n0 + lrow;
    if (wr < N) wv = *(const float4*)(W + (size_t)wr*ldw + k0 + lq*4);
    __syncthreads();
    Asl[lq*4+0][lrow] = av.x; Asl[lq*4+1][lrow] = av.y;
    Asl[lq*4+2][lrow] = av.z; Asl[lq*4+3][lrow] = av.w;
    Wsl[lq*4+0][lrow] = wv.x; Wsl[lq*4+1][lrow] = wv.y;
    Wsl[lq*4+2][lrow] = wv.z; Wsl[lq*4+3][lrow] = wv.w;
    __syncthreads();
#pragma unroll
    for (int kk = 0; kk < 16; ++kk) {
      float4 a4 = *(const float4*)&Asl[kk][ty*4];
      float4 w4 = *(const float4*)&Wsl[kk][tx*4];
      float a[4] = {a4.x, a4.y, a4.z, a4.w};
      float w[4] = {w4.x, w4.y, w4.z, w4.w};
#pragma unroll
      for (int i = 0; i < 4; ++i)
#pragma unroll
        for (int j = 0; j < 4; ++j)
          acc[i][j] += a[i]*w[j];
    }
  }

#pragma unroll
  for (int i = 0; i < 4; ++i) {
    int m = m0 + ty*4 + i;
    if (m >= M) continue;
    float* crow = C + (size_t)m*ldc;
    float bm = (ACT == 2) ? bias[m] : 0.f;
#pragma unroll
    for (int j = 0; j < 4; ++j) {
      int n = n0 + tx*4 + j;
      if (n >= N) continue;
      float val = acc[i][j];
      if (ACT == 2) {
        val += bm;
        val = (val > 20.f) ? val : log1pf(__expf(val));
      }
      crow[n] = val;
    }
  }
}

// ---------------- conv(4)+SiLU, sliding-window, bf16 input ----------------
__global__ __launch_bounds__(256) void conv_silu_kernel(const short* __restrict__ xzq,
                                                        const float* __restrict__ conv_w,
                                                        const float* __restrict__ conv_b,
                                                        float* __restrict__ uT,
                                                        short* __restrict__ ucq) {
  __shared__ float tile[64][65];
  int b  = blockIdx.z;
  int c0 = blockIdx.x * 64;
  int t0 = blockIdx.y * 64;
  int lx = threadIdx.x & 63;
  int ly = threadIdx.x >> 6;
  int c = c0 + lx;
  const int S = 2*DINNER;
  float w0 = conv_w[c*4+0], w1 = conv_w[c*4+1], w2 = conv_w[c*4+2], w3 = conv_w[c*4+3];
  float cb = conv_b[c];
  int ts = t0 + ly*16;
  const short* col = xzq + ((size_t)b*SEQL + ts) * S + c;
  float x3 = (ts >= 3) ? bf2f(col[-3*S]) : 0.f;
  float x2 = (ts >= 2) ? bf2f(col[-2*S]) : 0.f;
  float x1 = (ts >= 1) ? bf2f(col[-1*S]) : 0.f;
#pragma unroll
  for (int i = 0; i < 16; ++i) {
    float x0 = bf2f(col[(size_t)i*S]);
    float acc = cb + x3*w0 + x2*w1 + x1*w2 + x0*w3;
    float sig = 1.f / (1.f + __expf(-acc));
    float v = acc * sig;
    ucq[((size_t)b*SEQL + ts + i)*DINNER + c] = f2bf(v);
    tile[lx][ly*16 + i] = v;
    x3 = x2; x2 = x1; x1 = x0;
  }
  __syncthreads();
#pragma unroll
  for (int i = 0; i < 16; ++i) {
    int cl = ly*16 + i;
    uT[((size_t)(c0 + cl))*NTOK + (size_t)b*SEQL + t0 + lx] = tile[cl][lx];
  }
}

__device__ inline float readlane_f(float v, int l) {
  return __int_as_float(__builtin_amdgcn_readlane(__float_as_int(v), l));
}

// ---------------- Selective scan v13 (85 us structural floor) ----------------
#define CPB (DINNER/4)
__global__ __launch_bounds__(256) void scan_kernel(const float* __restrict__ dT,
                                                   const float* __restrict__ x_dbl,
                                                   const float* __restrict__ uT,
                                                   const float* __restrict__ A_log,
                                                   const float* __restrict__ Dp,
                                                   float* __restrict__ yT) {
  __shared__ float red_all[4][32*66 + 32];
  int tid  = threadIdx.x;
  int wave = tid >> 6;
  int lane = tid & 63;
  float* red = red_all[wave];
  int b = blockIdx.x / CPB;
  int c = (blockIdx.x % CPB) * 4 + wave;
  float Ac2 = -__expf(A_log[(size_t)c*64 + lane]) * 1.44269504f;
  float Dc = Dp[c];
  float h = 0.f;
  const float* dp = dT + (size_t)c * NTOK + (size_t)b * SEQL;
  const float* up = uT + (size_t)c * NTOK + (size_t)b * SEQL;
  float* yrow = yT + ((size_t)b*DINNER + c) * SEQL;
  const float* sbase = x_dbl + (size_t)b * SEQL * XDBL_P + DTRANK;

  float d_v = dp[lane];
  float u_v = up[lane];
  int off = lane;

  const int r = lane & 31, hs = lane >> 5;
  const int NBLK = SEQL/64;
  for (int tb = 0; tb < NBLK; ++tb) {
    int t0 = tb*64;
    float d_nxt = 0.f, u_nxt = 0.f;
    if (tb + 1 < NBLK) {
      d_nxt = dp[t0 + 64 + lane];
      u_nxt = up[t0 + 64 + lane];
    }
    float du_v = d_v * u_v;

#pragma unroll
    for (int half = 0; half < 2; ++half) {
#pragma unroll
      for (int k = 0; k < 32; ++k) {
        int i = half*32 + k;
        float Bv = sbase[off];
        float Cv = sbase[off + DSTATE];
        off += XDBL_P;
        float sd  = readlane_f(d_v,  i);
        float sdu = readlane_f(du_v, i);
        float dA = __builtin_amdgcn_exp2f(sd * Ac2);
        h = fmaf(dA, h, sdu * Bv);
        red[k*66 + lane] = h * Cv;
      }
      {
        const float2* rp2 = (const float2*)&red[r*66 + hs*32];
        float2 a0 = rp2[0], a1 = rp2[1];
#pragma unroll
        for (int jj = 1; jj < 8; ++jj) {
          float2 v0 = rp2[2*jj], v1 = rp2[2*jj + 1];
          a0.x += v0.x; a0.y += v0.y;
          a1.x += v1.x; a1.y += v1.y;
        }
        float y = (a0.x + a0.y) + (a1.x + a1.y);
        y += __shfl_xor(y, 32);
        float ut = __shfl(u_v, half*32 + r);
        y = fmaf(Dc, ut, y);
        if (lane < 32) yrow[t0 + half*32 + lane] = y;
      }
    }
    __syncthreads();
    d_v = d_nxt;
    u_v = u_nxt;
  }
}

// ---------------- gate: g = yT^T * silu(z) -> bf16 (float4 yT loads) ----------------
__global__ __launch_bounds__(256) void ymul_kernel(const float* __restrict__ yT,
                                                   const short* __restrict__ xzq,
                                                   short* __restrict__ g) {
  __shared__ float tile[64][65];
  int b  = blockIdx.z;
  int c0 = blockIdx.x * 64;
  int t0 = blockIdx.y * 64;
  int tid = threadIdx.x;
  int lx = tid & 63;
  int ly = tid >> 6;
  const float* src = yT + ((size_t)b*DINNER + c0) * SEQL + t0;
  {
    int row = tid >> 4;                 // 0..15
    int tq  = (tid & 15) * 4;           // 0,4,..,60
#pragma unroll
    for (int p = 0; p < 4; ++p) {
      int c = p*16 + row;
      float4 v = *(const float4*)&src[(size_t)c*SEQL + tq];
      tile[c][tq+0] = v.x; tile[c][tq+1] = v.y;
      tile[c][tq+2] = v.z; tile[c][tq+3] = v.w;
    }
  }
  __syncthreads();
  const int S = 2*DINNER;
#pragma unroll
  for (int i = 0; i < 16; ++i) {
    int t = ly*16 + i;
    float z = bf2f(xzq[((size_t)b*SEQL + t0 + t)*S + DINNER + c0 + lx]);
    float zs = z / (1.f + __expf(-z));
    g[((size_t)b*SEQL + t0 + t)*DINNER + c0 + lx] = f2bf(tile[lx][t] * zs);
  }
}

extern "C" void kernel_launch(void* const* d_in, const int* in_sizes, int n_in,
                              void* d_out, int out_size, void* d_ws, size_t ws_size,
                              hipStream_t stream) {
  const float* x      = (const float*)d_in[0];
  const float* gamma  = (const float*)d_in[1];
  const float* beta   = (const float*)d_in[2];
  const float* W_in   = (const float*)d_in[3];
  const float* conv_w = (const float*)d_in[4];
  const float* conv_b = (const float*)d_in[5];
  const float* W_x    = (const float*)d_in[6];
  const float* W_dt   = (const float*)d_in[7];
  const float* b_dt   = (const float*)d_in[8];
  const float* A_log  = (const float*)d_in[9];
  const float* Dvec   = (const float*)d_in[10];
  const float* W_out  = (const float*)d_in[11];
  float* out = (float*)d_out;

  float* ws = (float*)d_ws;
  float* uT    = ws;                                  // DINNER*NTOK f32
  float* xdbl  = uT    + (size_t)NTOK*1536;           // NTOK*192
  float* dltT  = xdbl  + (size_t)NTOK*XDBL_P;         // DINNER*NTOK
  float* yT    = dltT  + (size_t)NTOK*1536;           // NTOK*1536
  float* xpart = yT    + (size_t)NTOK*1536;           // 4 * NTOK*192
  short* xzq   = (short*)(xpart + (size_t)4*NTOK*XDBL_P);  // NTOK*3072 bf16
  short* xnq   = xzq  + (size_t)NTOK*3072;
  short* ucq   = xnq  + (size_t)NTOK*768;
  short* gq    = ucq  + (size_t)NTOK*1536;
  short* qin   = gq   + (size_t)NTOK*1536;
  short* qx    = qin  + (size_t)NW_IN;
  short* qout  = qx   + (size_t)NW_XP;

  // 1. fused LN + vectorized weight conversion
  prep_kernel<<<LN_BLOCKS + CVT_BLOCKS, 256, 0, stream>>>(
      x, gamma, beta, xnq, W_in, W_out, W_x, qin, qout, qx);
  // 2. xz = xn @ W_in^T  [2048 x 3072] -> bf16  (BN=128: fewer staged bytes/flop)
  gemm_mfma<128,true><<<dim3(3072/128, NTOK/128), 256, 0, stream>>>(
      xnq, qin, (float*)xzq, 3072, DIMD, DIMD, 0);
  // 3. conv + silu (bf16 in) -> ucq bf16, uT f32
  conv_silu_kernel<<<dim3(DINNER/64, SEQL/64, BATCH), 256, 0, stream>>>(
      xzq, conv_w, conv_b, uT, ucq);
  // 4. x_dbl partials, split-K=4
  gemm_mfma<64,false><<<dim3(XDBL_P/64, NTOK/128, 4), 256, 0, stream>>>(
      ucq, qx, xpart, XDBL_P, DINNER, DINNER/4, (size_t)NTOK*XDBL_P);
  reduce4_kernel<<<(NTOK*XDBL_P/4 + 255)/256, 256, 0, stream>>>(xpart, xdbl);
  // 5. deltaT = softplus(W_dt @ dt^T + b_dt)
  gemm_nt<2><<<dim3(NTOK/64, DINNER/64), 256, 0, stream>>>(W_dt, DTRANK, xdbl, XDBL_P, b_dt,
                                                           dltT, NTOK, DINNER, NTOK, DTRANK);
  // 6. selective scan
  scan_kernel<<<BATCH*DINNER/4, 256, 0, stream>>>(dltT, xdbl, uT, A_log, Dvec, yT);
  // 7. gate
  ymul_kernel<<<dim3(DINNER/64, SEQL/64, BATCH), 256, 0, stream>>>(yT, xzq, gq);
  // 8. out = g @ W_out^T
  gemm_mfma<64,false><<<dim3(DIMD/64, NTOK/128), 256, 0, stream>>>(
      gq, qout, out, DIMD, DINNER, DINNER, 0);
}

// Round 16
// 173.107 us; speedup vs baseline: 1.0447x; 1.0447x over previous
//
#include <hip/hip_runtime.h>
#include <math.h>

#define DIMD 768
#define DSTATE 64
#define DINNER 1536
#define DTRANK 48
#define BATCH 2
#define SEQL 1024
#define NTOK (BATCH*SEQL)
#define XDBL_P 192              // padded x_dbl row stride (176 -> 192)
#define EPSV 1e-5f

typedef __attribute__((ext_vector_type(8))) short bf16x8;
typedef __attribute__((ext_vector_type(4))) short s16x4;
typedef __attribute__((ext_vector_type(4))) float f32x4;

__device__ inline short f2bf(float f) {             // RTNE f32 -> bf16
  unsigned u = __float_as_uint(f);
  u = u + 0x7FFFu + ((u >> 16) & 1u);
  return (short)(u >> 16);
}
__device__ inline float bf2f(short s) {
  return __uint_as_float(((unsigned)(unsigned short)s) << 16);
}

// ---------------- prep: LayerNorm->bf16 (blocks 0..511) + vectorized weight cvt ----------------
#define NW_IN  (3072*768)
#define NW_OUT (768*1536)
#define NW_XP  (192*1536)
#define LN_BLOCKS (NTOK/4)
#define CVT_BLOCKS ((NW_IN+NW_OUT+NW_XP)/4/256)
__global__ __launch_bounds__(256) void prep_kernel(const float* __restrict__ x,
                                                   const float* __restrict__ gamma,
                                                   const float* __restrict__ beta,
                                                   short* __restrict__ xnq,
                                                   const float* __restrict__ Win,
                                                   const float* __restrict__ Wout,
                                                   const float* __restrict__ Wx,
                                                   short* __restrict__ qin,
                                                   short* __restrict__ qout,
                                                   short* __restrict__ qx) {
  if (blockIdx.x < LN_BLOCKS) {
    int wave = threadIdx.x >> 6;
    int lane = threadIdx.x & 63;
    int row = blockIdx.x * 4 + wave;
    const float* xr = x + (size_t)row * DIMD;
    float v[12];
    float s = 0.f, ss = 0.f;
#pragma unroll
    for (int i = 0; i < 12; ++i) {
      v[i] = xr[lane + i*64];
      s += v[i];
      ss += v[i]*v[i];
    }
#pragma unroll
    for (int m = 1; m < 64; m <<= 1) {
      s  += __shfl_xor(s, m);
      ss += __shfl_xor(ss, m);
    }
    float mu   = s * (1.f/DIMD);
    float var  = ss * (1.f/DIMD) - mu*mu;
    float rstd = rsqrtf(var + EPSV);
    short* o = xnq + (size_t)row * DIMD;
#pragma unroll
    for (int i = 0; i < 12; ++i) {
      int j = lane + i*64;
      o[j] = f2bf((v[i] - mu) * rstd * gamma[j] + beta[j]);
    }
    return;
  }
  int e = ((blockIdx.x - LN_BLOCKS) * 256 + threadIdx.x) * 4;   // 4 elems/thread
  const float* src;
  short* dst;
  if (e < NW_IN) { src = Win + e; dst = qin + e; }
  else if ((e -= NW_IN) < NW_OUT) { src = Wout + e; dst = qout + e; }
  else if ((e -= NW_OUT) < NW_XP) {
    int r = e / 1536;
    dst = qx + e;
    if (r >= 176) { *(s16x4*)dst = (s16x4){0,0,0,0}; return; }
    src = Wx + e;
  } else return;
  float4 v = *(const float4*)src;
  *(s16x4*)dst = (s16x4){f2bf(v.x), f2bf(v.y), f2bf(v.z), f2bf(v.w)};
}

// ---------------- bf16 MFMA NT GEMM, optional split-K, optional bf16 C ----------------
template<int BN, bool BF16OUT>
__global__ __launch_bounds__(256) void gemm_mfma(const short* __restrict__ A,
                                                 const short* __restrict__ B,
                                                 float* __restrict__ C, int ldc,
                                                 int Kfull, int Kchunk, size_t partStride) {
  constexpr int BM = 128, BK = 64;
  constexpr int WN = (BN == 128) ? 2 : 1;
  constexpr int WM = 4 / WN;
  constexpr int MFR = BM / (WM * 16);
  constexpr int NFR = BN / (WN * 16);
  constexpr int BSW = (BN * BK * 2) / 4096;
  __shared__ short As[BM * BK];
  __shared__ short Bs[BN * BK];
  const int tid  = threadIdx.x;
  const int wave = tid >> 6, lane = tid & 63;
  const int m0 = blockIdx.y * BM;
  const int n0 = blockIdx.x * BN;
  const int wm = wave / WN, wn = wave % WN;
  const int kBeg = blockIdx.z * Kchunk;
  const int kEnd = kBeg + Kchunk;
  C += (size_t)blockIdx.z * partStride;

  const short* aSrc = A + (size_t)(m0 + (tid >> 3)) * Kfull + (tid & 7) * 8;
  const short* bSrc = B + (size_t)(n0 + (tid >> 3)) * Kfull + (tid & 7) * 8;

  f32x4 acc[MFR][NFR];
#pragma unroll
  for (int i = 0; i < MFR; ++i)
#pragma unroll
    for (int j = 0; j < NFR; ++j)
      acc[i][j] = (f32x4){0.f, 0.f, 0.f, 0.f};

  for (int k0 = kBeg; k0 < kEnd; k0 += BK) {
#pragma unroll
    for (int s = 0; s < 4; ++s)
      __builtin_amdgcn_global_load_lds(
        (const __attribute__((address_space(1))) void*)(aSrc + (size_t)s*32*Kfull + k0),
        (__attribute__((address_space(3))) void*)((char*)As + s*4096 + wave*1024),
        16, 0, 0);
#pragma unroll
    for (int s = 0; s < BSW; ++s)
      __builtin_amdgcn_global_load_lds(
        (const __attribute__((address_space(1))) void*)(bSrc + (size_t)s*32*Kfull + k0),
        (__attribute__((address_space(3))) void*)((char*)Bs + s*4096 + wave*1024),
        16, 0, 0);
    __syncthreads();

#pragma unroll
    for (int kk = 0; kk < 2; ++kk) {
      bf16x8 af[MFR], bfr[NFR];
#pragma unroll
      for (int i = 0; i < MFR; ++i) {
        int r = wm * (BM / WM) + i * 16 + (lane & 15);
        af[i] = *(const bf16x8*)&As[r * BK + kk * 32 + (lane >> 4) * 8];
      }
#pragma unroll
      for (int j = 0; j < NFR; ++j) {
        int r = wn * (BN / WN) + j * 16 + (lane & 15);
        bfr[j] = *(const bf16x8*)&Bs[r * BK + kk * 32 + (lane >> 4) * 8];
      }
#pragma unroll
      for (int i = 0; i < MFR; ++i)
#pragma unroll
        for (int j = 0; j < NFR; ++j)
          acc[i][j] = __builtin_amdgcn_mfma_f32_16x16x32_bf16(af[i], bfr[j], acc[i][j], 0, 0, 0);
    }
    __syncthreads();
  }

  const int cn = lane & 15, cr4 = (lane >> 4) * 4;
#pragma unroll
  for (int i = 0; i < MFR; ++i)
#pragma unroll
    for (int j = 0; j < NFR; ++j)
#pragma unroll
      for (int r = 0; r < 4; ++r) {
        int m = m0 + wm * (BM / WM) + i * 16 + cr4 + r;
        int n = n0 + wn * (BN / WN) + j * 16 + cn;
        if constexpr (BF16OUT)
          ((short*)C)[(size_t)m * ldc + n] = f2bf(acc[i][j][r]);
        else
          C[(size_t)m * ldc + n] = acc[i][j][r];
      }
}

// ---------------- split-K partial reduce: out = p0+p1+p2+p3 (fixed order) ----------------
__global__ __launch_bounds__(256) void reduce4_kernel(const float* __restrict__ p,
                                                      float* __restrict__ outb, int n4) {
  int i = blockIdx.x * 256 + threadIdx.x;
  if (i >= n4) return;
  const float4* p4 = (const float4*)p;
  float4 a = p4[i];
  float4 b = p4[i + n4];
  float4 c = p4[i + 2*n4];
  float4 d = p4[i + 3*n4];
  float4 r;
  r.x = ((a.x + b.x) + c.x) + d.x;
  r.y = ((a.y + b.y) + c.y) + d.y;
  r.z = ((a.z + b.z) + c.z) + d.z;
  r.w = ((a.w + b.w) + c.w) + d.w;
  ((float4*)outb)[i] = r;
}

// ---------------- fp32 NT GEMM. ACT: 0 none, 2 = bias[m]+softplus (row bias) ----------------
template<int ACT>
__global__ __launch_bounds__(256) void gemm_nt(const float* __restrict__ A, int lda,
                                               const float* __restrict__ W, int ldw,
                                               const float* __restrict__ bias,
                                               float* __restrict__ C, int ldc,
                                               int M, int N, int K) {
  __shared__ float Asl[16][68];
  __shared__ float Wsl[16][68];
  int tid = threadIdx.x;
  int m0 = blockIdx.y * 64;
  int n0 = blockIdx.x * 64;
  int lrow = tid >> 2;
  int lq   = tid & 3;
  int tx = tid & 15;
  int ty = tid >> 4;
  float acc[4][4] = {{0.f}};

  for (int k0 = 0; k0 < K; k0 += 16) {
    float4 av = make_float4(0.f,0.f,0.f,0.f);
    int ar = m0 + lrow;
    if (ar < M) av = *(const float4*)(A + (size_t)ar*lda + k0 + lq*4);
    float4 wv = make_float4(0.f,0.f,0.f,0.f);
    int wr = n0 + lrow;
    if (wr < N) wv = *(const float4*)(W + (size_t)wr*ldw + k0 + lq*4);
    __syncthreads();
    Asl[lq*4+0][lrow] = av.x; Asl[lq*4+1][lrow] = av.y;
    Asl[lq*4+2][lrow] = av.z; Asl[lq*4+3][lrow] = av.w;
    Wsl[lq*4+0][lrow] = wv.x; Wsl[lq*4+1][lrow] = wv.y;
    Wsl[lq*4+2][lrow] = wv.z; Wsl[lq*4+3][lrow] = wv.w;
    __syncthreads();
#pragma unroll
    for (int kk = 0; kk < 16; ++kk) {
      float4 a4 = *(const float4*)&Asl[kk][ty*4];
      float4 w4 = *(const float4*)&Wsl[kk][tx*4];
      float a[4] = {a4.x, a4.y, a4.z, a4.w};
      float w[4] = {w4.x, w4.y, w4.z, w4.w};
#pragma unroll
      for (int i = 0; i < 4; ++i)
#pragma unroll
        for (int j = 0; j < 4; ++j)
          acc[i][j] += a[i]*w[j];
    }
  }

#pragma unroll
  for (int i = 0; i < 4; ++i) {
    int m = m0 + ty*4 + i;
    if (m >= M) continue;
    float* crow = C + (size_t)m*ldc;
    float bm = (ACT == 2) ? bias[m] : 0.f;
#pragma unroll
    for (int j = 0; j < 4; ++j) {
      int n = n0 + tx*4 + j;
      if (n >= N) continue;
      float val = acc[i][j];
      if (ACT == 2) {
        val += bm;
        val = (val > 20.f) ? val : log1pf(__expf(val));
      }
      crow[n] = val;
    }
  }
}

// ---------------- conv(4)+SiLU, sliding-window, bf16 input ----------------
__global__ __launch_bounds__(256) void conv_silu_kernel(const short* __restrict__ xzq,
                                                        const float* __restrict__ conv_w,
                                                        const float* __restrict__ conv_b,
                                                        float* __restrict__ uT,
                                                        short* __restrict__ ucq) {
  __shared__ float tile[64][65];
  int b  = blockIdx.z;
  int c0 = blockIdx.x * 64;
  int t0 = blockIdx.y * 64;
  int lx = threadIdx.x & 63;
  int ly = threadIdx.x >> 6;
  int c = c0 + lx;
  const int S = 2*DINNER;
  float w0 = conv_w[c*4+0], w1 = conv_w[c*4+1], w2 = conv_w[c*4+2], w3 = conv_w[c*4+3];
  float cb = conv_b[c];
  int ts = t0 + ly*16;
  const short* col = xzq + ((size_t)b*SEQL + ts) * S + c;
  float x3 = (ts >= 3) ? bf2f(col[-3*S]) : 0.f;
  float x2 = (ts >= 2) ? bf2f(col[-2*S]) : 0.f;
  float x1 = (ts >= 1) ? bf2f(col[-1*S]) : 0.f;
#pragma unroll
  for (int i = 0; i < 16; ++i) {
    float x0 = bf2f(col[(size_t)i*S]);
    float acc = cb + x3*w0 + x2*w1 + x1*w2 + x0*w3;
    float sig = 1.f / (1.f + __expf(-acc));
    float v = acc * sig;
    ucq[((size_t)b*SEQL + ts + i)*DINNER + c] = f2bf(v);
    tile[lx][ly*16 + i] = v;
    x3 = x2; x2 = x1; x1 = x0;
  }
  __syncthreads();
#pragma unroll
  for (int i = 0; i < 16; ++i) {
    int cl = ly*16 + i;
    uT[((size_t)(c0 + cl))*NTOK + (size_t)b*SEQL + t0 + lx] = tile[cl][lx];
  }
}

__device__ inline float readlane_f(float v, int l) {
  return __int_as_float(__builtin_amdgcn_readlane(__float_as_int(v), l));
}

// ---------------- Selective scan v13 (85 us structural floor) ----------------
#define CPB (DINNER/4)
__global__ __launch_bounds__(256) void scan_kernel(const float* __restrict__ dT,
                                                   const float* __restrict__ x_dbl,
                                                   const float* __restrict__ uT,
                                                   const float* __restrict__ A_log,
                                                   const float* __restrict__ Dp,
                                                   float* __restrict__ yT) {
  __shared__ float red_all[4][32*66 + 32];
  int tid  = threadIdx.x;
  int wave = tid >> 6;
  int lane = tid & 63;
  float* red = red_all[wave];
  int b = blockIdx.x / CPB;
  int c = (blockIdx.x % CPB) * 4 + wave;
  float Ac2 = -__expf(A_log[(size_t)c*64 + lane]) * 1.44269504f;
  float Dc = Dp[c];
  float h = 0.f;
  const float* dp = dT + (size_t)c * NTOK + (size_t)b * SEQL;
  const float* up = uT + (size_t)c * NTOK + (size_t)b * SEQL;
  float* yrow = yT + ((size_t)b*DINNER + c) * SEQL;
  const float* sbase = x_dbl + (size_t)b * SEQL * XDBL_P + DTRANK;

  float d_v = dp[lane];
  float u_v = up[lane];
  int off = lane;

  const int r = lane & 31, hs = lane >> 5;
  const int NBLK = SEQL/64;
  for (int tb = 0; tb < NBLK; ++tb) {
    int t0 = tb*64;
    float d_nxt = 0.f, u_nxt = 0.f;
    if (tb + 1 < NBLK) {
      d_nxt = dp[t0 + 64 + lane];
      u_nxt = up[t0 + 64 + lane];
    }
    float du_v = d_v * u_v;

#pragma unroll
    for (int half = 0; half < 2; ++half) {
#pragma unroll
      for (int k = 0; k < 32; ++k) {
        int i = half*32 + k;
        float Bv = sbase[off];
        float Cv = sbase[off + DSTATE];
        off += XDBL_P;
        float sd  = readlane_f(d_v,  i);
        float sdu = readlane_f(du_v, i);
        float dA = __builtin_amdgcn_exp2f(sd * Ac2);
        h = fmaf(dA, h, sdu * Bv);
        red[k*66 + lane] = h * Cv;
      }
      {
        const float2* rp2 = (const float2*)&red[r*66 + hs*32];
        float2 a0 = rp2[0], a1 = rp2[1];
#pragma unroll
        for (int jj = 1; jj < 8; ++jj) {
          float2 v0 = rp2[2*jj], v1 = rp2[2*jj + 1];
          a0.x += v0.x; a0.y += v0.y;
          a1.x += v1.x; a1.y += v1.y;
        }
        float y = (a0.x + a0.y) + (a1.x + a1.y);
        y += __shfl_xor(y, 32);
        float ut = __shfl(u_v, half*32 + r);
        y = fmaf(Dc, ut, y);
        if (lane < 32) yrow[t0 + half*32 + lane] = y;
      }
    }
    __syncthreads();
    d_v = d_nxt;
    u_v = u_nxt;
  }
}

// ---------------- gate: g = yT^T * silu(z) -> bf16 (float4 yT loads) ----------------
__global__ __launch_bounds__(256) void ymul_kernel(const float* __restrict__ yT,
                                                   const short* __restrict__ xzq,
                                                   short* __restrict__ g) {
  __shared__ float tile[64][65];
  int b  = blockIdx.z;
  int c0 = blockIdx.x * 64;
  int t0 = blockIdx.y * 64;
  int tid = threadIdx.x;
  int lx = tid & 63;
  int ly = tid >> 6;
  const float* src = yT + ((size_t)b*DINNER + c0) * SEQL + t0;
  {
    int row = tid >> 4;
    int tq  = (tid & 15) * 4;
#pragma unroll
    for (int p = 0; p < 4; ++p) {
      int c = p*16 + row;
      float4 v = *(const float4*)&src[(size_t)c*SEQL + tq];
      tile[c][tq+0] = v.x; tile[c][tq+1] = v.y;
      tile[c][tq+2] = v.z; tile[c][tq+3] = v.w;
    }
  }
  __syncthreads();
  const int S = 2*DINNER;
#pragma unroll
  for (int i = 0; i < 16; ++i) {
    int t = ly*16 + i;
    float z = bf2f(xzq[((size_t)b*SEQL + t0 + t)*S + DINNER + c0 + lx]);
    float zs = z / (1.f + __expf(-z));
    g[((size_t)b*SEQL + t0 + t)*DINNER + c0 + lx] = f2bf(tile[lx][t] * zs);
  }
}

extern "C" void kernel_launch(void* const* d_in, const int* in_sizes, int n_in,
                              void* d_out, int out_size, void* d_ws, size_t ws_size,
                              hipStream_t stream) {
  const float* x      = (const float*)d_in[0];
  const float* gamma  = (const float*)d_in[1];
  const float* beta   = (const float*)d_in[2];
  const float* W_in   = (const float*)d_in[3];
  const float* conv_w = (const float*)d_in[4];
  const float* conv_b = (const float*)d_in[5];
  const float* W_x    = (const float*)d_in[6];
  const float* W_dt   = (const float*)d_in[7];
  const float* b_dt   = (const float*)d_in[8];
  const float* A_log  = (const float*)d_in[9];
  const float* Dvec   = (const float*)d_in[10];
  const float* W_out  = (const float*)d_in[11];
  float* out = (float*)d_out;

  float* ws = (float*)d_ws;
  float* uT    = ws;                                  // DINNER*NTOK f32
  float* xdbl  = uT    + (size_t)NTOK*1536;           // NTOK*192
  float* dltT  = xdbl  + (size_t)NTOK*XDBL_P;         // DINNER*NTOK
  float* yT    = dltT  + (size_t)NTOK*1536;           // NTOK*1536
  float* xpart = yT    + (size_t)NTOK*1536;           // 4 * NTOK*768 (split-K partials, shared)
  short* xzq   = (short*)(xpart + (size_t)4*NTOK*DIMD);    // NTOK*3072 bf16
  short* xnq   = xzq  + (size_t)NTOK*3072;
  short* ucq   = xnq  + (size_t)NTOK*768;
  short* gq    = ucq  + (size_t)NTOK*1536;
  short* qin   = gq   + (size_t)NTOK*1536;
  short* qx    = qin  + (size_t)NW_IN;
  short* qout  = qx   + (size_t)NW_XP;

  // 1. fused LN + vectorized weight conversion
  prep_kernel<<<LN_BLOCKS + CVT_BLOCKS, 256, 0, stream>>>(
      x, gamma, beta, xnq, W_in, W_out, W_x, qin, qout, qx);
  // 2. xz = xn @ W_in^T  [2048 x 3072] -> bf16  (BN=64: 768 blocks = 3/CU exact balance)
  gemm_mfma<64,true><<<dim3(3072/64, NTOK/128), 256, 0, stream>>>(
      xnq, qin, (float*)xzq, 3072, DIMD, DIMD, 0);
  // 3. conv + silu (bf16 in) -> ucq bf16, uT f32
  conv_silu_kernel<<<dim3(DINNER/64, SEQL/64, BATCH), 256, 0, stream>>>(
      xzq, conv_w, conv_b, uT, ucq);
  // 4. x_dbl partials, split-K=4 -> reduce
  gemm_mfma<64,false><<<dim3(XDBL_P/64, NTOK/128, 4), 256, 0, stream>>>(
      ucq, qx, xpart, XDBL_P, DINNER, DINNER/4, (size_t)NTOK*XDBL_P);
  reduce4_kernel<<<(NTOK*XDBL_P/4 + 255)/256, 256, 0, stream>>>(xpart, xdbl, NTOK*XDBL_P/4);
  // 5. deltaT = softplus(W_dt @ dt^T + b_dt)
  gemm_nt<2><<<dim3(NTOK/64, DINNER/64), 256, 0, stream>>>(W_dt, DTRANK, xdbl, XDBL_P, b_dt,
                                                           dltT, NTOK, DINNER, NTOK, DTRANK);
  // 6. selective scan
  scan_kernel<<<BATCH*DINNER/4, 256, 0, stream>>>(dltT, xdbl, uT, A_log, Dvec, yT);
  // 7. gate
  ymul_kernel<<<dim3(DINNER/64, SEQL/64, BATCH), 256, 0, stream>>>(yT, xzq, gq);
  // 8. out = g @ W_out^T  [2048 x 768], split-K=4 (768 blocks = 3/CU) -> reduce into out
  gemm_mfma<64,false><<<dim3(DIMD/64, NTOK/128, 4), 256, 0, stream>>>(
      gq, qout, xpart, DIMD, DINNER, DINNER/4, (size_t)NTOK*DIMD);
  reduce4_kernel<<<(NTOK*DIMD/4 + 255)/256, 256, 0, stream>>>(xpart, out, NTOK*DIMD/4);
}